// Round 1
// baseline (370.777 us; speedup 1.0000x reference)
//
#include <hip/hip_runtime.h>
#include <stdint.h>

#define EMB 1024
#define SEQ 2048
#define NB 4
#define NH 16
#define HD 64
#define NGLOB 4
#define WIN 256
#define MTOT (NB*SEQ)   // 8192
#define NQKV (3*EMB)    // 3072

typedef __attribute__((ext_vector_type(8))) short bf16x8;
typedef __attribute__((ext_vector_type(4))) float f32x4;
typedef unsigned short u16;
typedef unsigned int u32;

__device__ __forceinline__ u16 f2bf(float f) {
  u32 u = __builtin_bit_cast(u32, f);
  u += 0x7fffu + ((u >> 16) & 1u);
  return (u16)(u >> 16);
}

#define MFMA16(a, b, c) __builtin_amdgcn_mfma_f32_16x16x32_bf16(a, b, c, 0, 0, 0)
#define GLD16(g, l) __builtin_amdgcn_global_load_lds( \
    (const __attribute__((address_space(1))) void*)(g), \
    (__attribute__((address_space(3))) void*)(l), 16, 0, 0)

// ---------------- cast fp32 -> bf16 (vectorized) ----------------
__global__ void k_cast(const float* __restrict__ in, u16* __restrict__ out, int n4) {
  int i = blockIdx.x * blockDim.x + threadIdx.x;
  if (i >= n4) return;
  float4 f = ((const float4*)in)[i];
  ushort4 o;
  o.x = f2bf(f.x); o.y = f2bf(f.y); o.z = f2bf(f.z); o.w = f2bf(f.w);
  ((ushort4*)out)[i] = o;
}

// ---------------- transpose + cast: w[R][C] -> wt[C][R] bf16 ----------------
__global__ void k_transpose_cast(const float* __restrict__ w, u16* __restrict__ wt,
                                 int R, int C) {
  __shared__ float tile[32][33];
  int c0 = blockIdx.x * 32, r0 = blockIdx.y * 32;
  int tx = threadIdx.x, ty = threadIdx.y;  // 32 x 8
  #pragma unroll
  for (int j = 0; j < 32; j += 8)
    tile[ty + j][tx] = w[(size_t)(r0 + ty + j) * C + (c0 + tx)];
  __syncthreads();
  #pragma unroll
  for (int j = 0; j < 32; j += 8)
    wt[(size_t)(c0 + ty + j) * R + (r0 + tx)] = f2bf(tile[tx][ty + j]);
}

// ---------------- 128x128 bf16 MFMA GEMM, K=1024, B given transposed ----------------
// EPI==0: epilogue scatters into Q [bh][s][d], K [bh][s][d], Vt [bh][d][s] (bf16)
// EPI==1: epilogue writes fp32 out[m][n] = acc + bias[n]
template <int EPI>
__global__ __launch_bounds__(256, 2) void k_gemm(
    const u16* __restrict__ A, const u16* __restrict__ Bt,
    const float* __restrict__ bias,
    u16* __restrict__ Qo, u16* __restrict__ Ko, u16* __restrict__ Vt,
    float* __restrict__ outp) {
  __shared__ __align__(16) u16 ldsA[128 * 64];
  __shared__ __align__(16) u16 ldsB[128 * 64];
  const int tid = threadIdx.x;
  const int w = tid >> 6, lane = tid & 63;
  const int wm = w >> 1, wn = w & 1;
  const int m0 = blockIdx.x * 128, n0 = blockIdx.y * 128;
  const int rq = lane & 15, g = lane >> 4;

  // staging source swizzle (rule #21: linear LDS dest, inverse-swizzled source)
  const int srow = lane >> 3;                    // row within 8-row group
  const int scol = ((lane & 7) ^ srow) << 3;     // swizzled element offset in row

  f32x4 acc[4][4] = {};
  char* ldsAb = (char*)ldsA;
  char* ldsBb = (char*)ldsB;

  for (int k0 = 0; k0 < EMB; k0 += 64) {
    #pragma unroll
    for (int it = 0; it < 4; ++it) {
      int t = w * 4 + it;                 // 0..15 instr id, 8 rows each
      int row = t * 8 + srow;
      GLD16(A + (size_t)(m0 + row) * EMB + k0 + scol, ldsAb + t * 1024);
      GLD16(Bt + (size_t)(n0 + row) * EMB + k0 + scol, ldsBb + t * 1024);
    }
    __syncthreads();
    #pragma unroll
    for (int ks = 0; ks < 2; ++ks) {
      bf16x8 af[4], bfr[4];
      #pragma unroll
      for (int i = 0; i < 4; ++i) {
        int rowA = wm * 64 + i * 16 + rq;
        int off = (ks * 64 + (g << 4)) ^ ((rowA & 7) << 4);
        af[i] = *(const bf16x8*)(ldsAb + rowA * 128 + off);
        int rowB = wn * 64 + i * 16 + rq;
        int offb = (ks * 64 + (g << 4)) ^ ((rowB & 7) << 4);
        bfr[i] = *(const bf16x8*)(ldsBb + rowB * 128 + offb);
      }
      #pragma unroll
      for (int mi = 0; mi < 4; ++mi)
        #pragma unroll
        for (int ni = 0; ni < 4; ++ni)
          acc[mi][ni] = MFMA16(af[mi], bfr[ni], acc[mi][ni]);
    }
    __syncthreads();
  }

  // epilogue: D layout row=(lane>>4)*4+i, col=lane&15 (verified m89/m91)
  #pragma unroll
  for (int ni = 0; ni < 4; ++ni) {
    int col = n0 + wn * 64 + ni * 16 + rq;
    float bv = bias[col];
    if (EPI == 0) {
      int part = col >> 10;
      int hh = (col & 1023) >> 6;
      int d = col & 63;
      #pragma unroll
      for (int mi = 0; mi < 4; ++mi) {
        #pragma unroll
        for (int i = 0; i < 4; ++i) {
          int m = m0 + wm * 64 + mi * 16 + g * 4 + i;
          int b = m >> 11, s = m & 2047;
          u16 val = f2bf(acc[mi][ni][i] + bv);
          size_t bh = (size_t)(b * NH + hh);
          if (part == 0)      Qo[(bh * SEQ + s) * HD + d] = val;
          else if (part == 1) Ko[(bh * SEQ + s) * HD + d] = val;
          else                Vt[(bh * HD + d) * SEQ + s] = val;
        }
      }
    } else {
      #pragma unroll
      for (int mi = 0; mi < 4; ++mi)
        #pragma unroll
        for (int i = 0; i < 4; ++i) {
          int m = m0 + wm * 64 + mi * 16 + g * 4 + i;
          outp[(size_t)m * EMB + col] = acc[mi][ni][i] + bv;
        }
    }
  }
}

// ---------------- flash attention: 1 wave = 16 query rows ----------------
__global__ __launch_bounds__(256, 2) void k_attn(
    const u16* __restrict__ Q, const u16* __restrict__ K,
    const u16* __restrict__ Vt, u16* __restrict__ ctx) {
  __shared__ __align__(16) u16 plds[4][2][16][16];  // [wave][keytile][q][key]
  const int w = threadIdx.x >> 6, lane = threadIdx.x & 63;
  const int rq = lane & 15, g = lane >> 4;
  const int gid = blockIdx.x;
  const int bh = gid >> 5;                 // 0..63
  const int qb = (gid & 31) * 64 + w * 16; // wave's query base
  const int h = bh & 15;
  const bool isloc = (h >= NGLOB);

  const u16* Qp = Q + (size_t)bh * SEQ * HD;
  const u16* Kp = K + (size_t)bh * SEQ * HD;
  const u16* Vp = Vt + (size_t)bh * HD * SEQ;

  // Q fragments: A[row=lane&15][k = ks*32 + (lane>>4)*8 + i]
  bf16x8 qf[2];
  {
    int qrow = qb + rq;
    qf[0] = *(const bf16x8*)(Qp + (size_t)qrow * HD + g * 8);
    qf[1] = *(const bf16x8*)(Qp + (size_t)qrow * HD + 32 + g * 8);
  }

  f32x4 acc[4] = {};
  float mrow[4] = {-__builtin_inff(), -__builtin_inff(), -__builtin_inff(), -__builtin_inff()};
  float lrow[4] = {0.f, 0.f, 0.f, 0.f};

  int klo = 0;
  if (isloc && qb > WIN) klo = (qb - WIN) & ~31;
  const int khi = qb + 16;

  for (int kc = klo; kc < khi; kc += 32) {
    f32x4 sc[2];
    #pragma unroll
    for (int t = 0; t < 2; ++t) {
      int key = kc + t * 16 + rq;
      const u16* kptr = Kp + (size_t)key * HD + g * 8;
      bf16x8 kf0 = *(const bf16x8*)(kptr);
      bf16x8 kf1 = *(const bf16x8*)(kptr + 32);
      f32x4 s = {};
      s = MFMA16(qf[0], kf0, s);
      s = MFMA16(qf[1], kf1, s);
      sc[t] = s;
    }
    // scale + mask (D row = g*4+i -> query, col = rq -> key)
    #pragma unroll
    for (int t = 0; t < 2; ++t) {
      int key = kc + t * 16 + rq;
      #pragma unroll
      for (int i = 0; i < 4; ++i) {
        int q = qb + g * 4 + i;
        float v = sc[t][i] * 0.125f;
        bool msk = (key > q) || (isloc && (q - key > WIN));
        sc[t][i] = msk ? -__builtin_inff() : v;
      }
    }
    // online softmax per query row (16-lane subgroup reductions)
    float f[4];
    #pragma unroll
    for (int i = 0; i < 4; ++i) {
      float cm = fmaxf(sc[0][i], sc[1][i]);
      cm = fmaxf(cm, __shfl_xor(cm, 1));
      cm = fmaxf(cm, __shfl_xor(cm, 2));
      cm = fmaxf(cm, __shfl_xor(cm, 4));
      cm = fmaxf(cm, __shfl_xor(cm, 8));
      float mn = fmaxf(mrow[i], cm);
      float mu = (mn == -__builtin_inff()) ? 0.f : mn;
      float mo = (mrow[i] == -__builtin_inff()) ? mu : mrow[i];
      f[i] = __expf(mo - mu);
      mrow[i] = mn;
      float p0 = __expf(sc[0][i] - mu);
      float p1 = __expf(sc[1][i] - mu);
      sc[0][i] = p0; sc[1][i] = p1;
      float ps = p0 + p1;
      ps += __shfl_xor(ps, 1);
      ps += __shfl_xor(ps, 2);
      ps += __shfl_xor(ps, 4);
      ps += __shfl_xor(ps, 8);
      lrow[i] = lrow[i] * f[i] + ps;
    }
    #pragma unroll
    for (int dt = 0; dt < 4; ++dt) {
      f32x4 a = acc[dt];
      a[0] *= f[0]; a[1] *= f[1]; a[2] *= f[2]; a[3] *= f[3];
      acc[dt] = a;
    }
    // P -> LDS (transpose to PV A-operand layout), wave-local, no barrier
    #pragma unroll
    for (int t = 0; t < 2; ++t)
      #pragma unroll
      for (int i = 0; i < 4; ++i)
        plds[w][t][g * 4 + i][rq] = f2bf(sc[t][i]);
    // read P as A-frag: row=rq, keys g*8..g*8+7
    bf16x8 pa = *(const bf16x8*)(&plds[w][g >> 1][rq][(g & 1) * 8]);
    // PV: B[k=key][n=d] = Vt[d][key], contiguous 8 keys per lane
    #pragma unroll
    for (int dt = 0; dt < 4; ++dt) {
      bf16x8 vf = *(const bf16x8*)(Vp + (size_t)(dt * 16 + rq) * SEQ + kc + g * 8);
      acc[dt] = MFMA16(pa, vf, acc[dt]);
    }
  }

  // normalize + write ctx [b][s][e] bf16
  const int b = bh >> 4;
  #pragma unroll
  for (int dt = 0; dt < 4; ++dt) {
    #pragma unroll
    for (int i = 0; i < 4; ++i) {
      int s = qb + g * 4 + i;
      int e = h * HD + dt * 16 + rq;
      float o = acc[dt][i] / lrow[i];
      ctx[(size_t)(b * SEQ + s) * EMB + e] = f2bf(o);
    }
  }
}

extern "C" void kernel_launch(void* const* d_in, const int* in_sizes, int n_in,
                              void* d_out, int out_size, void* d_ws, size_t ws_size,
                              hipStream_t stream) {
  const float* x     = (const float*)d_in[0];
  const float* w_qkv = (const float*)d_in[1];
  const float* b_qkv = (const float*)d_in[2];
  const float* w_out = (const float*)d_in[3];
  const float* b_out = (const float*)d_in[4];
  float* out = (float*)d_out;

  char* ws = (char*)d_ws;
  u16* xb    = (u16*)(ws);                              // 16 MiB
  u16* wqkvT = (u16*)(ws + (16ull << 20));              // 6 MiB
  u16* woutT = (u16*)(ws + (22ull << 20));              // 2 MiB
  u16* Qb    = (u16*)(ws + (24ull << 20));              // 16 MiB
  u16* Kb    = (u16*)(ws + (40ull << 20));              // 16 MiB
  u16* Vt    = (u16*)(ws + (56ull << 20));              // 16 MiB
  u16* ctx   = (u16*)(ws + (72ull << 20));              // 16 MiB -> 88 MiB total

  k_cast<<<(MTOT * EMB / 4) / 256, 256, 0, stream>>>(x, xb, MTOT * EMB / 4);
  dim3 tb(32, 8);
  k_transpose_cast<<<dim3(NQKV / 32, EMB / 32), tb, 0, stream>>>(w_qkv, wqkvT, EMB, NQKV);
  k_transpose_cast<<<dim3(EMB / 32, EMB / 32), tb, 0, stream>>>(w_out, woutT, EMB, EMB);

  k_gemm<0><<<dim3(MTOT / 128, NQKV / 128), 256, 0, stream>>>(
      xb, wqkvT, b_qkv, Qb, Kb, Vt, nullptr);

  k_attn<<<dim3(NB * NH * (SEQ / 64)), 256, 0, stream>>>(Qb, Kb, Vt, ctx);

  k_gemm<1><<<dim3(MTOT / 128, EMB / 128), 256, 0, stream>>>(
      ctx, woutT, b_out, nullptr, nullptr, nullptr, out);
}

// Round 3
// 346.900 us; speedup vs baseline: 1.0688x; 1.0688x over previous
//
#include <hip/hip_runtime.h>
#include <stdint.h>

#define EMB 1024
#define SEQ 2048
#define NB 4
#define NH 16
#define HD 64
#define NGLOB 4
#define WIN 256
#define MTOT (NB*SEQ)   // 8192
#define NQKV (3*EMB)    // 3072

typedef __attribute__((ext_vector_type(8))) short bf16x8;
typedef __attribute__((ext_vector_type(4))) float f32x4;
typedef __attribute__((ext_vector_type(16))) float f32x16;
typedef unsigned short u16;
typedef unsigned int u32;

__device__ __forceinline__ u16 f2bf(float f) {
  u32 u = __builtin_bit_cast(u32, f);
  u += 0x7fffu + ((u >> 16) & 1u);
  return (u16)(u >> 16);
}

// pack two floats into one dword of two bf16 (low = a, high = b)
__device__ __forceinline__ u32 pack2bf(float a, float b) {
  return (u32)f2bf(a) | ((u32)f2bf(b) << 16);
}

#define MFMA16(a, b, c) __builtin_amdgcn_mfma_f32_16x16x32_bf16(a, b, c, 0, 0, 0)
#define MFMA32(a, b, c) __builtin_amdgcn_mfma_f32_32x32x16_bf16(a, b, c, 0, 0, 0)
#define GLD16(g, l) __builtin_amdgcn_global_load_lds( \
    (const __attribute__((address_space(1))) void*)(g), \
    (__attribute__((address_space(3))) void*)(l), 16, 0, 0)

// ---------------- cast fp32 -> bf16 (vectorized) ----------------
__global__ void k_cast(const float* __restrict__ in, u16* __restrict__ out, int n4) {
  int i = blockIdx.x * blockDim.x + threadIdx.x;
  if (i >= n4) return;
  float4 f = ((const float4*)in)[i];
  ushort4 o;
  o.x = f2bf(f.x); o.y = f2bf(f.y); o.z = f2bf(f.z); o.w = f2bf(f.w);
  ((ushort4*)out)[i] = o;
}

// ---------------- transpose + cast: w[R][C] -> wt[C][R] bf16 ----------------
__global__ void k_transpose_cast(const float* __restrict__ w, u16* __restrict__ wt,
                                 int R, int C) {
  __shared__ float tile[32][33];
  int c0 = blockIdx.x * 32, r0 = blockIdx.y * 32;
  int tx = threadIdx.x, ty = threadIdx.y;  // 32 x 8
  #pragma unroll
  for (int j = 0; j < 32; j += 8)
    tile[ty + j][tx] = w[(size_t)(r0 + ty + j) * C + (c0 + tx)];
  __syncthreads();
  #pragma unroll
  for (int j = 0; j < 32; j += 8)
    wt[(size_t)(c0 + ty + j) * R + (r0 + tx)] = f2bf(tile[tx][ty + j]);
}

// ---------------- 128x128 bf16 MFMA GEMM, K=1024, B given transposed ----------------
template <int EPI>
__global__ __launch_bounds__(256, 2) void k_gemm(
    const u16* __restrict__ A, const u16* __restrict__ Bt,
    const float* __restrict__ bias,
    u16* __restrict__ Qo, u16* __restrict__ Ko, u16* __restrict__ Vt,
    float* __restrict__ outp) {
  __shared__ __align__(16) u16 ldsA[128 * 64];
  __shared__ __align__(16) u16 ldsB[128 * 64];
  const int tid = threadIdx.x;
  const int w = tid >> 6, lane = tid & 63;
  const int wm = w >> 1, wn = w & 1;
  const int m0 = blockIdx.x * 128, n0 = blockIdx.y * 128;
  const int rq = lane & 15, g = lane >> 4;

  const int srow = lane >> 3;
  const int scol = ((lane & 7) ^ srow) << 3;

  f32x4 acc[4][4] = {};
  char* ldsAb = (char*)ldsA;
  char* ldsBb = (char*)ldsB;

  for (int k0 = 0; k0 < EMB; k0 += 64) {
    #pragma unroll
    for (int it = 0; it < 4; ++it) {
      int t = w * 4 + it;
      int row = t * 8 + srow;
      GLD16(A + (size_t)(m0 + row) * EMB + k0 + scol, ldsAb + t * 1024);
      GLD16(Bt + (size_t)(n0 + row) * EMB + k0 + scol, ldsBb + t * 1024);
    }
    __syncthreads();
    #pragma unroll
    for (int ks = 0; ks < 2; ++ks) {
      bf16x8 af[4], bfr[4];
      #pragma unroll
      for (int i = 0; i < 4; ++i) {
        int rowA = wm * 64 + i * 16 + rq;
        int off = (ks * 64 + (g << 4)) ^ ((rowA & 7) << 4);
        af[i] = *(const bf16x8*)(ldsAb + rowA * 128 + off);
        int rowB = wn * 64 + i * 16 + rq;
        int offb = (ks * 64 + (g << 4)) ^ ((rowB & 7) << 4);
        bfr[i] = *(const bf16x8*)(ldsBb + rowB * 128 + offb);
      }
      #pragma unroll
      for (int mi = 0; mi < 4; ++mi)
        #pragma unroll
        for (int ni = 0; ni < 4; ++ni)
          acc[mi][ni] = MFMA16(af[mi], bfr[ni], acc[mi][ni]);
    }
    __syncthreads();
  }

  #pragma unroll
  for (int ni = 0; ni < 4; ++ni) {
    int col = n0 + wn * 64 + ni * 16 + rq;
    float bv = bias[col];
    if (EPI == 0) {
      int part = col >> 10;
      int hh = (col & 1023) >> 6;
      int d = col & 63;
      #pragma unroll
      for (int mi = 0; mi < 4; ++mi) {
        #pragma unroll
        for (int i = 0; i < 4; ++i) {
          int m = m0 + wm * 64 + mi * 16 + g * 4 + i;
          int b = m >> 11, s = m & 2047;
          u16 val = f2bf(acc[mi][ni][i] + bv);
          size_t bh = (size_t)(b * NH + hh);
          if (part == 0)      Qo[(bh * SEQ + s) * HD + d] = val;
          else if (part == 1) Ko[(bh * SEQ + s) * HD + d] = val;
          else                Vt[(bh * HD + d) * SEQ + s] = val;
        }
      }
    } else {
      #pragma unroll
      for (int mi = 0; mi < 4; ++mi)
        #pragma unroll
        for (int i = 0; i < 4; ++i) {
          int m = m0 + wm * 64 + mi * 16 + g * 4 + i;
          outp[(size_t)m * EMB + col] = acc[mi][ni][i] + bv;
        }
    }
  }
}

// ---------------- flash attention: 1 wave = 32 query rows, swapped QK^T,
// in-register softmax; half-wave exchange via __shfl_xor only ----------------
__global__ __launch_bounds__(256, 4) void k_attn(
    const u16* __restrict__ Q, const u16* __restrict__ K,
    const u16* __restrict__ Vt, u16* __restrict__ ctx) {
  const int w = threadIdx.x >> 6, lane = threadIdx.x & 63;
  const int l31 = lane & 31;
  const int hi = lane >> 5;
  const bool hib = hi != 0;
  const int hi8 = hi * 8, hi4 = hi * 4;

  const int gid = blockIdx.x;
  const int bh = gid >> 4;
  const int qt = (gid & 15) * 4 + w;
  const int qb = qt * 32;
  const int h = bh & 15;
  const int b = bh >> 4;
  const bool isloc = (h >= NGLOB);

  const u16* Qp = Q + (size_t)bh * SEQ * HD;
  const u16* Kp = K + (size_t)bh * SEQ * HD;
  const u16* Vp = Vt + (size_t)bh * HD * SEQ;

  const int q = qb + l31;

  // Q as B-operand: col=q (lane&31), k = j*16 + hi*8 + i
  bf16x8 qf[4];
  #pragma unroll
  for (int j = 0; j < 4; ++j)
    qf[j] = *(const bf16x8*)(Qp + (size_t)q * HD + j * 16 + hi8);

  f32x16 oacc[2] = {};
  float m = -__builtin_inff();
  float l = 0.f;

  int klo = 0;
  if (isloc && qb > WIN) klo = qb - WIN;

  for (int kc = klo; kc <= qb; kc += 32) {
    // S^T = K . Q^T : A = K rows (32 keys), B = Q cols (32 queries)
    f32x16 s = {};
    #pragma unroll
    for (int j = 0; j < 4; ++j) {
      bf16x8 kf = *(const bf16x8*)(Kp + (size_t)(kc + l31) * HD + j * 16 + hi8);
      s = MFMA32(kf, qf[j], s);
    }

    // lane holds key rows koff[r] = hi4 + (r&3) + 8*(r>>2), col = q
    float p[16];
    float cmax = -__builtin_inff();
    #pragma unroll
    for (int r = 0; r < 16; ++r) {
      int key = kc + hi4 + (r & 3) + 8 * (r >> 2);
      float v = s[r] * 0.125f;
      bool msk = (key > q) || (isloc && (q - key > WIN));
      p[r] = msk ? -__builtin_inff() : v;
      cmax = fmaxf(cmax, p[r]);
    }
    // merge max across lane halves (verified primitive)
    cmax = fmaxf(cmax, __shfl_xor(cmax, 32));

    float mn = fmaxf(m, cmax);
    float mu = (mn == -__builtin_inff()) ? 0.f : mn;
    float f = __expf(((m == -__builtin_inff()) ? mu : m) - mu);
    m = mn;

    float psum = 0.f;
    #pragma unroll
    for (int r = 0; r < 16; ++r) {
      p[r] = __expf(p[r] - mu);
      psum += p[r];
    }
    psum += __shfl_xor(psum, 32);
    l = l * f + psum;

    #pragma unroll
    for (int dt = 0; dt < 2; ++dt)
      #pragma unroll
      for (int r = 0; r < 16; ++r)
        oacc[dt][r] *= f;

    // P^T B-fragments: pack own pairs, exchange halves via shfl_xor(32)
    union { u32 u[4]; bf16x8 v; } pbf[2];
    #pragma unroll
    for (int sl = 0; sl < 2; ++sl) {
      int s8 = sl * 8;
      u32 X0 = pack2bf(p[s8 + 0], p[s8 + 1]);   // keys 4hi+0, 4hi+1   (+16*sl)
      u32 X1 = pack2bf(p[s8 + 2], p[s8 + 3]);   // keys 4hi+2, 4hi+3
      u32 X2 = pack2bf(p[s8 + 4], p[s8 + 5]);   // keys 8+4hi+0, 8+4hi+1
      u32 X3 = pack2bf(p[s8 + 6], p[s8 + 7]);   // keys 8+4hi+2, 8+4hi+3
      u32 oX0 = (u32)__shfl_xor((int)X0, 32);
      u32 oX1 = (u32)__shfl_xor((int)X1, 32);
      u32 oX2 = (u32)__shfl_xor((int)X2, 32);
      u32 oX3 = (u32)__shfl_xor((int)X3, 32);
      // B-frag dword j must hold keys (hi*8 + 2j, hi*8 + 2j + 1)
      pbf[sl].u[0] = hib ? oX2 : X0;
      pbf[sl].u[1] = hib ? oX3 : X1;
      pbf[sl].u[2] = hib ? X2 : oX0;
      pbf[sl].u[3] = hib ? X3 : oX1;
    }

    // O^T += V^T . P^T : A = Vt rows (d), B = P^T (keys x queries)
    #pragma unroll
    for (int dt = 0; dt < 2; ++dt) {
      #pragma unroll
      for (int sl = 0; sl < 2; ++sl) {
        bf16x8 vf = *(const bf16x8*)(Vp + (size_t)(dt * 32 + l31) * SEQ + kc + sl * 16 + hi8);
        oacc[dt] = MFMA32(vf, pbf[sl].v, oacc[dt]);
      }
    }
  }

  // normalize + write ctx[b][s][e]; O^T: col=q (lane), row d = dt*32 + koff[r]
  float linv = 1.f / l;
  #pragma unroll
  for (int dt = 0; dt < 2; ++dt) {
    #pragma unroll
    for (int r = 0; r < 16; ++r) {
      int d = dt * 32 + hi4 + (r & 3) + 8 * (r >> 2);
      int e = h * HD + d;
      ctx[(size_t)(b * SEQ + q) * EMB + e] = f2bf(oacc[dt][r] * linv);
    }
  }
}

extern "C" void kernel_launch(void* const* d_in, const int* in_sizes, int n_in,
                              void* d_out, int out_size, void* d_ws, size_t ws_size,
                              hipStream_t stream) {
  const float* x     = (const float*)d_in[0];
  const float* w_qkv = (const float*)d_in[1];
  const float* b_qkv = (const float*)d_in[2];
  const float* w_out = (const float*)d_in[3];
  const float* b_out = (const float*)d_in[4];
  float* out = (float*)d_out;

  char* ws = (char*)d_ws;
  u16* xb    = (u16*)(ws);
  u16* wqkvT = (u16*)(ws + (16ull << 20));
  u16* woutT = (u16*)(ws + (22ull << 20));
  u16* Qb    = (u16*)(ws + (24ull << 20));
  u16* Kb    = (u16*)(ws + (40ull << 20));
  u16* Vt    = (u16*)(ws + (56ull << 20));
  u16* ctx   = (u16*)(ws + (72ull << 20));

  k_cast<<<(MTOT * EMB / 4) / 256, 256, 0, stream>>>(x, xb, MTOT * EMB / 4);
  dim3 tb(32, 8);
  k_transpose_cast<<<dim3(NQKV / 32, EMB / 32), tb, 0, stream>>>(w_qkv, wqkvT, EMB, NQKV);
  k_transpose_cast<<<dim3(EMB / 32, EMB / 32), tb, 0, stream>>>(w_out, woutT, EMB, EMB);

  k_gemm<0><<<dim3(MTOT / 128, NQKV / 128), 256, 0, stream>>>(
      xb, wqkvT, b_qkv, Qb, Kb, Vt, nullptr);

  k_attn<<<dim3(NB * NH * (SEQ / 128)), 256, 0, stream>>>(Qb, Kb, Vt, ctx);

  k_gemm<1><<<dim3(MTOT / 128, EMB / 128), 256, 0, stream>>>(
      ctx, woutT, b_out, nullptr, nullptr, nullptr, out);
}

// Round 4
// 212.114 us; speedup vs baseline: 1.7480x; 1.6354x over previous
//
#include <hip/hip_runtime.h>
#include <stdint.h>

#define EMB 1024
#define SEQ 2048
#define NB 4
#define NH 16
#define HD 64
#define NGLOB 4
#define WIN 256
#define MTOT (NB*SEQ)   // 8192
#define NQKV (3*EMB)    // 3072

typedef __attribute__((ext_vector_type(8))) short bf16x8;
typedef __attribute__((ext_vector_type(4))) float f32x4;
typedef __attribute__((ext_vector_type(16))) float f32x16;
typedef unsigned short u16;
typedef unsigned int u32;

__device__ __forceinline__ u16 f2bf(float f) {
  u32 u = __builtin_bit_cast(u32, f);
  u += 0x7fffu + ((u >> 16) & 1u);
  return (u16)(u >> 16);
}

__device__ __forceinline__ u32 pack2bf(float a, float b) {
  return (u32)f2bf(a) | ((u32)f2bf(b) << 16);
}

#define MFMA16(a, b, c) __builtin_amdgcn_mfma_f32_16x16x32_bf16(a, b, c, 0, 0, 0)
#define MFMA32(a, b, c) __builtin_amdgcn_mfma_f32_32x32x16_bf16(a, b, c, 0, 0, 0)
#define GLD16(g, l) __builtin_amdgcn_global_load_lds( \
    (const __attribute__((address_space(1))) void*)(g), \
    (__attribute__((address_space(3))) void*)(l), 16, 0, 0)

// ---------------- cast fp32 -> bf16 (vectorized) ----------------
__global__ void k_cast(const float* __restrict__ in, u16* __restrict__ out, int n4) {
  int i = blockIdx.x * blockDim.x + threadIdx.x;
  if (i >= n4) return;
  float4 f = ((const float4*)in)[i];
  ushort4 o;
  o.x = f2bf(f.x); o.y = f2bf(f.y); o.z = f2bf(f.z); o.w = f2bf(f.w);
  ((ushort4*)out)[i] = o;
}

// ---------------- transpose + cast: w[R][C] -> wt[C][R] bf16 ----------------
__global__ void k_transpose_cast(const float* __restrict__ w, u16* __restrict__ wt,
                                 int R, int C) {
  __shared__ float tile[32][33];
  int c0 = blockIdx.x * 32, r0 = blockIdx.y * 32;
  int tx = threadIdx.x, ty = threadIdx.y;  // 32 x 8
  #pragma unroll
  for (int j = 0; j < 32; j += 8)
    tile[ty + j][tx] = w[(size_t)(r0 + ty + j) * C + (c0 + tx)];
  __syncthreads();
  #pragma unroll
  for (int j = 0; j < 32; j += 8)
    wt[(size_t)(c0 + ty + j) * R + (r0 + tx)] = f2bf(tile[tx][ty + j]);
}

// ---------------- 128x128 bf16 MFMA GEMM, K=1024, B given transposed ----------------
template <int EPI>
__global__ __launch_bounds__(256, 2) void k_gemm(
    const u16* __restrict__ A, const u16* __restrict__ Bt,
    const float* __restrict__ bias,
    u16* __restrict__ Qo, u16* __restrict__ Ko, u16* __restrict__ Vt,
    float* __restrict__ outp) {
  __shared__ __align__(16) u16 ldsA[128 * 64];
  __shared__ __align__(16) u16 ldsB[128 * 64];
  const int tid = threadIdx.x;
  const int w = tid >> 6, lane = tid & 63;
  const int wm = w >> 1, wn = w & 1;
  const int m0 = blockIdx.x * 128, n0 = blockIdx.y * 128;
  const int rq = lane & 15, g = lane >> 4;

  const int srow = lane >> 3;
  const int scol = ((lane & 7) ^ srow) << 3;

  f32x4 acc[4][4] = {};
  char* ldsAb = (char*)ldsA;
  char* ldsBb = (char*)ldsB;

  for (int k0 = 0; k0 < EMB; k0 += 64) {
    #pragma unroll
    for (int it = 0; it < 4; ++it) {
      int t = w * 4 + it;
      int row = t * 8 + srow;
      GLD16(A + (size_t)(m0 + row) * EMB + k0 + scol, ldsAb + t * 1024);
      GLD16(Bt + (size_t)(n0 + row) * EMB + k0 + scol, ldsBb + t * 1024);
    }
    __syncthreads();
    #pragma unroll
    for (int ks = 0; ks < 2; ++ks) {
      bf16x8 af[4], bfr[4];
      #pragma unroll
      for (int i = 0; i < 4; ++i) {
        int rowA = wm * 64 + i * 16 + rq;
        int off = (ks * 64 + (g << 4)) ^ ((rowA & 7) << 4);
        af[i] = *(const bf16x8*)(ldsAb + rowA * 128 + off);
        int rowB = wn * 64 + i * 16 + rq;
        int offb = (ks * 64 + (g << 4)) ^ ((rowB & 7) << 4);
        bfr[i] = *(const bf16x8*)(ldsBb + rowB * 128 + offb);
      }
      #pragma unroll
      for (int mi = 0; mi < 4; ++mi)
        #pragma unroll
        for (int ni = 0; ni < 4; ++ni)
          acc[mi][ni] = MFMA16(af[mi], bfr[ni], acc[mi][ni]);
    }
    __syncthreads();
  }

  #pragma unroll
  for (int ni = 0; ni < 4; ++ni) {
    int col = n0 + wn * 64 + ni * 16 + rq;
    float bv = bias[col];
    if (EPI == 0) {
      int part = col >> 10;
      int hh = (col & 1023) >> 6;
      int d = col & 63;
      #pragma unroll
      for (int mi = 0; mi < 4; ++mi) {
        #pragma unroll
        for (int i = 0; i < 4; ++i) {
          int m = m0 + wm * 64 + mi * 16 + g * 4 + i;
          int b = m >> 11, s = m & 2047;
          u16 val = f2bf(acc[mi][ni][i] + bv);
          size_t bh = (size_t)(b * NH + hh);
          if (part == 0)      Qo[(bh * SEQ + s) * HD + d] = val;
          else if (part == 1) Ko[(bh * SEQ + s) * HD + d] = val;
          else                Vt[(bh * HD + d) * SEQ + s] = val;
        }
      }
    } else {
      #pragma unroll
      for (int mi = 0; mi < 4; ++mi)
        #pragma unroll
        for (int i = 0; i < 4; ++i) {
          int m = m0 + wm * 64 + mi * 16 + g * 4 + i;
          outp[(size_t)m * EMB + col] = acc[mi][ni][i] + bv;
        }
    }
  }
}

// ---------------- flash attention: 1 wave = 32 query rows, swapped QK^T,
// in-register softmax; balanced wave->task mapping ----------------
__global__ __launch_bounds__(256, 4) void k_attn(
    const u16* __restrict__ Q, const u16* __restrict__ K,
    const u16* __restrict__ Vt, u16* __restrict__ ctx) {
  const int w = threadIdx.x >> 6, lane = threadIdx.x & 63;
  const int l31 = lane & 31;
  const int hi = lane >> 5;
  const bool hib = hi != 0;
  const int hi8 = hi * 8, hi4 = hi * 4;

  // ---- balanced task mapping ----
  // 4096 wave-tasks: 1024 global (bg 0..15, qt 0..63; len qt+1 chunks),
  //                  3072 local  (bl 0..47, qt 0..63; len <= 9 chunks).
  // type = gid>>8 so each CU's 4 co-resident blocks are one of each type.
  // Types 0/1: {global(q0), global(63-q0), local, local} rotated across waves.
  const int gid = blockIdx.x;
  const int type = gid >> 8;
  const int k = gid & 255;
  int bh, qt;
  if (type < 2) {
    int pk = type * 256 + k;           // 0..511 global pair index
    int bg = pk & 15;
    int q0 = pk >> 4;                  // 0..31
    int sel = (w + k) & 3;
    if (sel < 2) {
      bh = (bg >> 2) * 16 + (bg & 3);  // b = bg>>2, h = bg&3 (global head)
      qt = sel == 0 ? q0 : 63 - q0;
    } else {
      int lidx = pk * 2 + (sel - 2);   // 0..1023
      int bl = lidx >> 6;
      bh = (bl / 12) * 16 + 4 + (bl % 12);
      qt = lidx & 63;
    }
  } else {
    int bk = (type - 2) * 256 + k;     // 0..511
    int lidx = 1024 + bk * 4 + w;      // 1024..3071
    int bl = lidx >> 6;
    bh = (bl / 12) * 16 + 4 + (bl % 12);
    qt = lidx & 63;
  }

  const int qb = qt * 32;
  const int h = bh & 15;
  const int b = bh >> 4;
  const bool isloc = (h >= NGLOB);

  const u16* Qp = Q + (size_t)bh * SEQ * HD;
  const u16* Kp = K + (size_t)bh * SEQ * HD;
  const u16* Vp = Vt + (size_t)bh * HD * SEQ;

  const int q = qb + l31;

  // Q as B-operand: col=q (lane&31), k = j*16 + hi*8 + i
  bf16x8 qf[4];
  #pragma unroll
  for (int j = 0; j < 4; ++j)
    qf[j] = *(const bf16x8*)(Qp + (size_t)q * HD + j * 16 + hi8);

  f32x16 oacc[2] = {};
  float m = -__builtin_inff();
  float l = 0.f;

  int klo = 0;
  if (isloc && qb > WIN) klo = qb - WIN;

  for (int kc = klo; kc <= qb; kc += 32) {
    // S^T = K . Q^T : A = K rows (32 keys), B = Q cols (32 queries)
    f32x16 s = {};
    #pragma unroll
    for (int j = 0; j < 4; ++j) {
      bf16x8 kf = *(const bf16x8*)(Kp + (size_t)(kc + l31) * HD + j * 16 + hi8);
      s = MFMA32(kf, qf[j], s);
    }

    // lane holds key rows koff[r] = hi4 + (r&3) + 8*(r>>2), col = q
    float p[16];
    float cmax = -__builtin_inff();
    #pragma unroll
    for (int r = 0; r < 16; ++r) {
      int key = kc + hi4 + (r & 3) + 8 * (r >> 2);
      float v = s[r] * 0.125f;
      bool msk = (key > q) || (isloc && (q - key > WIN));
      p[r] = msk ? -__builtin_inff() : v;
      cmax = fmaxf(cmax, p[r]);
    }
    cmax = fmaxf(cmax, __shfl_xor(cmax, 32));

    // defer-max (T13): skip rescale when no column's max grew past m+8
    float mu;
    if (__any(cmax > m + 8.f)) {
      float mn = fmaxf(m, cmax);
      mu = (mn == -__builtin_inff()) ? 0.f : mn;
      float f = __expf(((m == -__builtin_inff()) ? mu : m) - mu);
      m = mn;
      l *= f;
      #pragma unroll
      for (int dt = 0; dt < 2; ++dt)
        #pragma unroll
        for (int r = 0; r < 16; ++r)
          oacc[dt][r] *= f;
    } else {
      mu = (m == -__builtin_inff()) ? 0.f : m;
    }

    float psum = 0.f;
    #pragma unroll
    for (int r = 0; r < 16; ++r) {
      p[r] = __expf(p[r] - mu);
      psum += p[r];
    }
    psum += __shfl_xor(psum, 32);
    l += psum;

    // P^T B-fragments: pack own pairs, exchange halves via shfl_xor(32)
    union { u32 u[4]; bf16x8 v; } pbf[2];
    #pragma unroll
    for (int sl = 0; sl < 2; ++sl) {
      int s8 = sl * 8;
      u32 X0 = pack2bf(p[s8 + 0], p[s8 + 1]);
      u32 X1 = pack2bf(p[s8 + 2], p[s8 + 3]);
      u32 X2 = pack2bf(p[s8 + 4], p[s8 + 5]);
      u32 X3 = pack2bf(p[s8 + 6], p[s8 + 7]);
      u32 oX0 = (u32)__shfl_xor((int)X0, 32);
      u32 oX1 = (u32)__shfl_xor((int)X1, 32);
      u32 oX2 = (u32)__shfl_xor((int)X2, 32);
      u32 oX3 = (u32)__shfl_xor((int)X3, 32);
      pbf[sl].u[0] = hib ? oX2 : X0;
      pbf[sl].u[1] = hib ? oX3 : X1;
      pbf[sl].u[2] = hib ? X2 : oX0;
      pbf[sl].u[3] = hib ? X3 : oX1;
    }

    // O^T += V^T . P^T : A = Vt rows (d), B = P^T (keys x queries)
    #pragma unroll
    for (int dt = 0; dt < 2; ++dt) {
      #pragma unroll
      for (int sl = 0; sl < 2; ++sl) {
        bf16x8 vf = *(const bf16x8*)(Vp + (size_t)(dt * 32 + l31) * SEQ + kc + sl * 16 + hi8);
        oacc[dt] = MFMA32(vf, pbf[sl].v, oacc[dt]);
      }
    }
  }

  // normalize + write ctx[b][s][e]
  float linv = 1.f / l;
  #pragma unroll
  for (int dt = 0; dt < 2; ++dt) {
    #pragma unroll
    for (int r = 0; r < 16; ++r) {
      int d = dt * 32 + hi4 + (r & 3) + 8 * (r >> 2);
      int e = h * HD + d;
      ctx[(size_t)(b * SEQ + q) * EMB + e] = f2bf(oacc[dt][r] * linv);
    }
  }
}

extern "C" void kernel_launch(void* const* d_in, const int* in_sizes, int n_in,
                              void* d_out, int out_size, void* d_ws, size_t ws_size,
                              hipStream_t stream) {
  const float* x     = (const float*)d_in[0];
  const float* w_qkv = (const float*)d_in[1];
  const float* b_qkv = (const float*)d_in[2];
  const float* w_out = (const float*)d_in[3];
  const float* b_out = (const float*)d_in[4];
  float* out = (float*)d_out;

  char* ws = (char*)d_ws;
  u16* xb    = (u16*)(ws);
  u16* wqkvT = (u16*)(ws + (16ull << 20));
  u16* woutT = (u16*)(ws + (22ull << 20));
  u16* Qb    = (u16*)(ws + (24ull << 20));
  u16* Kb    = (u16*)(ws + (40ull << 20));
  u16* Vt    = (u16*)(ws + (56ull << 20));
  u16* ctx   = (u16*)(ws + (72ull << 20));

  k_cast<<<(MTOT * EMB / 4) / 256, 256, 0, stream>>>(x, xb, MTOT * EMB / 4);
  dim3 tb(32, 8);
  k_transpose_cast<<<dim3(NQKV / 32, EMB / 32), tb, 0, stream>>>(w_qkv, wqkvT, EMB, NQKV);
  k_transpose_cast<<<dim3(EMB / 32, EMB / 32), tb, 0, stream>>>(w_out, woutT, EMB, EMB);

  k_gemm<0><<<dim3(MTOT / 128, NQKV / 128), 256, 0, stream>>>(
      xb, wqkvT, b_qkv, Qb, Kb, Vt, nullptr);

  k_attn<<<dim3(NB * NH * (SEQ / 128)), 256, 0, stream>>>(Qb, Kb, Vt, ctx);

  k_gemm<1><<<dim3(MTOT / 128, EMB / 128), 256, 0, stream>>>(
      ctx, woutT, b_out, nullptr, nullptr, nullptr, out);
}